// Round 10
// baseline (247.755 us; speedup 1.0000x reference)
//
#include <hip/hip_runtime.h>
#include <hip/hip_bf16.h>

#define H_   16
#define D_   64
#define HID  1024
#define S_   2048
#define B_   2
#define M_   (B_*S_)
#define ROT  32
#define LOG2E 1.44269504088896341f
#define QSCALE (0.125f * LOG2E)

typedef __bf16 bf16x8 __attribute__((ext_vector_type(8)));
typedef float  f32x4  __attribute__((ext_vector_type(4)));

// ---- workspace layout (bytes) — round-5 proven map, no overlays ----
#define XB_OFF   0u                       // Xb bf16 [4096][1024]           8 MiB
#define WQT_OFF  (8u<<20)                 // Wq^T bf16 (QKV contiguous)     2 MiB
#define WKT_OFF  (10u<<20)
#define WVT_OFF  (12u<<20)
#define WOT_OFF  (14u<<20)
#define F_OFF    (16u<<20)                // rotary factors f32 [B][S][32]  512 KiB
#define QH_OFF   ((16u<<20) + (1u<<19))   // Q bf16 [B][H][S][D]            8 MiB
#define KH_OFF   (QH_OFF + (8u<<20))      // K bf16 [B][H][S][D]            8 MiB
#define VT_OFF   (KH_OFF + (8u<<20))      // V bf16 [B][H][D][S]            8 MiB
#define AB_OFF   (VT_OFF + (8u<<20))      // attn out bf16 [4096][1024]     8 MiB

__device__ __forceinline__ float fexp2(float x) {
#if __has_builtin(__builtin_amdgcn_exp2f)
  return __builtin_amdgcn_exp2f(x);
#else
  return __expf(x * 0.69314718055994531f);
#endif
}

__device__ __forceinline__ unsigned pk2(float a, float b) {
  union { unsigned u; __bf16 h[2]; } w;
  w.h[0] = (__bf16)a; w.h[1] = (__bf16)b;
  return w.u;
}

// ---------------- fused prep: convx | rotf | wtrans | biaschk ----------------
// flat grid: [0,4096) convx, [4096,4608) rotf, [4608,8704) wtrans, [8704,10752) biaschk
__global__ __launch_bounds__(256) void prep_kernel(const float* __restrict__ x,
                                                   const float* __restrict__ sinu,
                                                   const float* __restrict__ abias,
                                                   const float* __restrict__ W0, const float* __restrict__ W1,
                                                   const float* __restrict__ W2, const float* __restrict__ W3,
                                                   __hip_bfloat16* __restrict__ xb,
                                                   float* __restrict__ F,
                                                   __hip_bfloat16* __restrict__ T0, __hip_bfloat16* __restrict__ T1,
                                                   __hip_bfloat16* __restrict__ T2, __hip_bfloat16* __restrict__ T3,
                                                   int* __restrict__ flag) {
  __shared__ float tile[32][33];
  int idx = blockIdx.x;
  int tid = threadIdx.x;
  if (idx < 4096) {                       // ---- convx: x f32 -> bf16
    int i = (idx * 256 + tid) * 4;
    float4 v = *(const float4*)(x + i);
    union { __hip_bfloat16 h[4]; uint2 u; } o;
    o.h[0] = __float2bfloat16(v.x);
    o.h[1] = __float2bfloat16(v.y);
    o.h[2] = __float2bfloat16(v.z);
    o.h[3] = __float2bfloat16(v.w);
    *(uint2*)(xb + i) = o.u;
  } else if (idx < 4608) {                // ---- rotf: F = cos + (d odd ? sin : -sin)
    int i = (idx - 4096) * 256 + tid;
    int d  = i & (ROT-1);
    int bs = i >> 5;
    int s  = bs & (S_-1);
    int b  = bs >> 11;
    float sn = sinu[(((size_t)b*2 + 0)*S_ + s)*ROT + d];
    float cs = sinu[(((size_t)b*2 + 1)*S_ + s)*ROT + d];
    F[i] = cs + ((d & 1) ? sn : -sn);
  } else if (idx < 8704) {                // ---- wtrans: W[k][n] f32 -> Wt[n][k] bf16
    int widx = idx - 4608;
    int z    = widx >> 10;
    int rem  = widx & 1023;
    const float* W = (z==0) ? W0 : (z==1) ? W1 : (z==2) ? W2 : W3;
    __hip_bfloat16* T = (z==0) ? T0 : (z==1) ? T1 : (z==2) ? T2 : T3;
    int bx = (rem & 31) * 32;
    int by = (rem >> 5) * 32;
    int tx = tid & 31, ty = tid >> 5;
    #pragma unroll
    for (int i = 0; i < 4; i++)
      tile[ty + i*8][tx] = W[(size_t)(by + ty + i*8)*HID + bx + tx];
    __syncthreads();
    #pragma unroll
    for (int i = 0; i < 4; i++)
      T[(size_t)(bx + ty + i*8)*HID + by + tx] = __float2bfloat16(tile[tx][ty + i*8]);
  } else {                                // ---- biaschk: OR all bias bits
    size_t i = ((size_t)(idx - 8704) * 256 + tid) * 16;
    const uint4* p = (const uint4*)(abias + i);
    unsigned acc = 0;
    #pragma unroll
    for (int j = 0; j < 4; j++) {
      uint4 u = p[j];
      acc |= u.x | u.y | u.z | u.w;
    }
    if (acc) *flag = 1;
  }
}

// ---------------- m97-style 128x128 QKV GEMM, fused epilogue ----------------
// V blocks (proj==2): normal operand order — C rows = s, packs 4 consecutive s at
// fixed d for the transposed Vt store. Q/K blocks: SWAPPED operands (C^T) — C rows
// = d (4 consecutive per lane), enabling float4 bias/F loads + packed 8B stores.
// A/B fragment lane layouts are identical on gfx950, so the swap is free.
__global__ __launch_bounds__(256) void qkv_kernel(const __hip_bfloat16* __restrict__ A,
                                                  const __hip_bfloat16* __restrict__ Bt,
                                                  const float* __restrict__ bq,
                                                  const float* __restrict__ bk,
                                                  const float* __restrict__ bv,
                                                  const float* __restrict__ F,
                                                  __hip_bfloat16* __restrict__ Qh,
                                                  __hip_bfloat16* __restrict__ Kh,
                                                  __hip_bfloat16* __restrict__ Vt) {
  __shared__ __align__(16) __bf16 Asm[2][128*32];
  __shared__ __align__(16) __bf16 Bsm[2][128*32];
  int tid  = threadIdx.x;
  int lane = tid & 63;
  int wv   = tid >> 6;
  int lr   = lane & 15;
  int qd   = lane >> 4;
  int row0 = blockIdx.y * 128;
  int col0 = blockIdx.x * 128;
  int wrow = (wv >> 1) * 64;
  int wcol = (wv & 1) * 64;
  int proj = col0 >> 10;               // 0=Q 1=K 2=V (block-uniform)

  int cg = ((tid & 3) ^ ((tid >> 2) & 3)) * 8;
  const __bf16* Ag = (const __bf16*)A  + (size_t)(row0 + (tid >> 2)) * HID + cg;
  const __bf16* Bg = (const __bf16*)Bt + (size_t)(col0 + (tid >> 2)) * HID + cg;

  f32x4 acc[4][4] = {};

  auto stage = [&](int buf, int k0) {
    __builtin_amdgcn_global_load_lds(Ag + k0,                  &Asm[buf][wv*512],        16, 0, 0);
    __builtin_amdgcn_global_load_lds(Ag + (size_t)64*HID + k0, &Asm[buf][2048 + wv*512], 16, 0, 0);
    __builtin_amdgcn_global_load_lds(Bg + k0,                  &Bsm[buf][wv*512],        16, 0, 0);
    __builtin_amdgcn_global_load_lds(Bg + (size_t)64*HID + k0, &Bsm[buf][2048 + wv*512], 16, 0, 0);
  };

  stage(0, 0);
  int buf = 0;
  for (int k0 = 0; k0 < HID; k0 += 32, buf ^= 1) {
    __syncthreads();
    if (k0 + 32 < HID) stage(buf ^ 1, k0 + 32);
    const __bf16* As = &Asm[buf][0];
    const __bf16* Bs = &Bsm[buf][0];
    bf16x8 a[4], b[4];
    #pragma unroll
    for (int i = 0; i < 4; i++) {
      int row = wrow + i*16 + lr;
      a[i] = *(const bf16x8*)(As + row*32 + ((qd ^ (row & 3)) * 8));
    }
    #pragma unroll
    for (int t = 0; t < 4; t++) {
      int row = wcol + t*16 + lr;
      b[t] = *(const bf16x8*)(Bs + row*32 + ((qd ^ (row & 3)) * 8));
    }
    if (proj == 2) {
      #pragma unroll
      for (int i = 0; i < 4; i++)
        #pragma unroll
        for (int t = 0; t < 4; t++)
          acc[i][t] = __builtin_amdgcn_mfma_f32_16x16x32_bf16(a[i], b[t], acc[i][t], 0, 0, 0);
    } else {
      #pragma unroll
      for (int i = 0; i < 4; i++)
        #pragma unroll
        for (int t = 0; t < 4; t++)
          acc[i][t] = __builtin_amdgcn_mfma_f32_16x16x32_bf16(b[t], a[i], acc[i][t], 0, 0, 0);
    }
  }

  int nb = (col0 & 1023) + wcol;
  if (proj == 2) {
    // ---- V epilogue (normal orientation): rows=s, col=d; pack 4 s at fixed d ----
    #pragma unroll
    for (int i = 0; i < 4; i++) {
      #pragma unroll
      for (int t = 0; t < 4; t++) {
        int nl = nb + t*16 + lr;
        int h  = nl >> 6, d = nl & 63;
        int m0 = row0 + wrow + i*16 + qd*4;
        int b2 = m0 >> 11, s0 = m0 & (S_-1);
        float bb = bv[nl];
        union { uint2 u; __bf16 hh[4]; } w;
        #pragma unroll
        for (int r = 0; r < 4; r++)
          w.hh[r] = (__bf16)(acc[i][t][r] + bb);
        *(uint2*)((__bf16*)Vt + ((size_t)(b2*H_ + h)*D_ + d)*S_ + s0) = w.u;
      }
    }
  } else {
    // ---- Q/K epilogue (swapped, C^T): rows=d (4 consecutive per lane), col=s ----
    __hip_bfloat16* dst = (proj == 0) ? Qh : Kh;
    const float* bias = (proj == 0) ? bq : bk;
    #pragma unroll
    for (int i = 0; i < 4; i++) {
      int sg = row0 + wrow + i*16 + lr;
      int b2 = sg >> 11, s = sg & (S_-1);
      #pragma unroll
      for (int t = 0; t < 4; t++) {
        int nl0 = nb + t*16 + qd*4;          // 4-aligned, within one head
        int h   = nl0 >> 6, d4 = nl0 & 63;
        float4 bb = *(const float4*)(bias + nl0);
        float v0 = acc[i][t][0] + bb.x;
        float v1 = acc[i][t][1] + bb.y;
        float v2 = acc[i][t][2] + bb.z;
        float v3 = acc[i][t][3] + bb.w;
        if (d4 < ROT) {
          float4 fv = *(const float4*)(F + ((size_t)(b2*S_ + s))*ROT + d4);
          v0 *= fv.x; v1 *= fv.y; v2 *= fv.z; v3 *= fv.w;
        }
        if (proj == 0) { v0 *= QSCALE; v1 *= QSCALE; v2 *= QSCALE; v3 *= QSCALE; }
        union { uint2 u; __bf16 hh[4]; } w;
        w.hh[0] = (__bf16)v0; w.hh[1] = (__bf16)v1;
        w.hh[2] = (__bf16)v2; w.hh[3] = (__bf16)v3;
        *(uint2*)((__bf16*)dst + ((size_t)(b2*H_ + h)*S_ + s)*D_ + d4) = w.u;
      }
    }
  }
}

// ---------------- out-proj GEMM: 128x64 tiles, SWAPPED operands, float4 stores ----
__global__ __launch_bounds__(256) void gemm_o64(const __hip_bfloat16* __restrict__ A,
                                                const __hip_bfloat16* __restrict__ Bt,
                                                float* __restrict__ outf) {
  __shared__ __align__(16) __bf16 Asm[2][128*32];
  __shared__ __align__(16) __bf16 Bsm[2][64*32];
  int tid  = threadIdx.x;
  int lane = tid & 63;
  int wv   = tid >> 6;
  int lr   = lane & 15;
  int qd   = lane >> 4;
  int row0 = blockIdx.y * 128;
  int col0 = blockIdx.x * 64;
  int cg = ((tid & 3) ^ ((tid >> 2) & 3)) * 8;
  const __bf16* Ag = (const __bf16*)A  + (size_t)(row0 + (tid >> 2)) * HID + cg;
  const __bf16* Bg = (const __bf16*)Bt + (size_t)(col0 + (tid >> 2)) * HID + cg;

  f32x4 acc[2][4] = {};
  auto stage = [&](int buf, int k0) {
    __builtin_amdgcn_global_load_lds(Ag + k0,                  &Asm[buf][wv*512],        16, 0, 0);
    __builtin_amdgcn_global_load_lds(Ag + (size_t)64*HID + k0, &Asm[buf][2048 + wv*512], 16, 0, 0);
    __builtin_amdgcn_global_load_lds(Bg + k0,                  &Bsm[buf][wv*512],        16, 0, 0);
  };
  stage(0, 0);
  int buf = 0;
  for (int k0 = 0; k0 < HID; k0 += 32, buf ^= 1) {
    __syncthreads();
    if (k0 + 32 < HID) stage(buf ^ 1, k0 + 32);
    const __bf16* As = &Asm[buf][0];
    const __bf16* Bs = &Bsm[buf][0];
    bf16x8 a[2], b[4];
    #pragma unroll
    for (int i = 0; i < 2; i++) {
      int row = wv*32 + i*16 + lr;
      a[i] = *(const bf16x8*)(As + row*32 + ((qd ^ (row & 3)) * 8));
    }
    #pragma unroll
    for (int t = 0; t < 4; t++) {
      int row = t*16 + lr;
      b[t] = *(const bf16x8*)(Bs + row*32 + ((qd ^ (row & 3)) * 8));
    }
    #pragma unroll
    for (int i = 0; i < 2; i++)
      #pragma unroll
      for (int t = 0; t < 4; t++)
        acc[i][t] = __builtin_amdgcn_mfma_f32_16x16x32_bf16(b[t], a[i], acc[i][t], 0, 0, 0);
  }
  // C^T: rows = n (4 consecutive per lane), col = m
  #pragma unroll
  for (int i = 0; i < 2; i++) {
    int m = row0 + wv*32 + i*16 + lr;
    #pragma unroll
    for (int t = 0; t < 4; t++) {
      int n = col0 + t*16 + qd*4;
      float4 v;
      v.x = acc[i][t][0]; v.y = acc[i][t][1];
      v.z = acc[i][t][2]; v.w = acc[i][t][3];
      *(float4*)(outf + (size_t)m*HID + n) = v;
    }
  }
}

// ---------------- flash attention: pipelined PV (one iter behind), grid 512 ----------------
// Proven round-9 kernel, unchanged.
#define PSTRIDE 72
__global__ __launch_bounds__(256) void flash_kernel(const __hip_bfloat16* __restrict__ Qh,
                                                    const __hip_bfloat16* __restrict__ Kh,
                                                    const __hip_bfloat16* __restrict__ Vt,
                                                    const float* __restrict__ abias,
                                                    const int* __restrict__ flag,
                                                    __hip_bfloat16* __restrict__ Ab) {
  __shared__ __align__(16) __bf16 Ksm[2][64*64];
  __shared__ __align__(16) __bf16 Vsm[2][64*64];
  __shared__ __align__(16) __bf16 Pb[2][4][32*PSTRIDE];
  int tid  = threadIdx.x;
  int lane = tid & 63;
  int wv   = tid >> 6;
  int lr   = lane & 15;
  int qd   = lane >> 4;
  int idx  = blockIdx.x;              // 0..511
  int xcd  = idx & 7;
  int slot = idx >> 3;                // 0..63
  int bh   = xcd * 4 + (slot >> 4);
  int qblk = slot & 15;
  int b  = bh >> 4;
  int h  = bh & 15;
  int q0 = qblk * 128 + wv * 32;

  const __bf16* Kbase = (const __bf16*)Kh + (size_t)bh*S_*D_;
  const __bf16* Vbase = (const __bf16*)Vt + (size_t)bh*D_*S_;

  const __bf16* Qp = (const __bf16*)Qh + ((size_t)bh*S_ + q0 + lr)*D_ + qd*8;
  bf16x8 qa00 = *(const bf16x8*)(Qp);
  bf16x8 qa01 = *(const bf16x8*)(Qp + 32);
  bf16x8 qa10 = *(const bf16x8*)(Qp + 16*D_);
  bf16x8 qa11 = *(const bf16x8*)(Qp + 16*D_ + 32);

  int hasbias = *flag;
  const float* bp0 = abias + (size_t)b*S_*S_ + (size_t)(q0 + lr)*S_;
  const float* bp1 = bp0 + (size_t)16*S_;

  int rowb = tid >> 3;
  int cg8  = ((tid & 7) ^ (rowb & 7)) * 8;

  auto stageKV = [&](int bf, int kt2) {
    __builtin_amdgcn_global_load_lds(Kbase + (size_t)(kt2 + rowb)*D_ + cg8,      &Ksm[bf][wv*512],        16, 0, 0);
    __builtin_amdgcn_global_load_lds(Kbase + (size_t)(kt2 + 32 + rowb)*D_ + cg8, &Ksm[bf][2048 + wv*512], 16, 0, 0);
    __builtin_amdgcn_global_load_lds(Vbase + (size_t)rowb*S_ + kt2 + cg8,        &Vsm[bf][wv*512],        16, 0, 0);
    __builtin_amdgcn_global_load_lds(Vbase + (size_t)(32 + rowb)*S_ + kt2 + cg8, &Vsm[bf][2048 + wv*512], 16, 0, 0);
  };

  f32x4 oacc0[4] = {}, oacc1[4] = {};
  float lsum0 = 0.f, lsum1 = 0.f;
  bf16x8 vp0[4], vp1[4];              // V frags of previous iteration (registers)
  int sw = lr & 7;

  stageKV(0, 0);
  int buf = 0;
  for (int kt = 0; kt < S_; kt += 64, buf ^= 1) {
    __syncthreads();                   // staged buf ready; P(prev) drained too
    if (kt + 64 < S_) stageKV(buf ^ 1, kt + 64);
    int pcur = (kt >> 6) & 1;
    __bf16* Pc = &Pb[pcur][wv][0];
    const __bf16* Pp = &Pb[pcur ^ 1][wv][0];

    // --- scores for current tile ---
    bf16x8 kf0[4], kf1[4];
    #pragma unroll
    for (int c = 0; c < 4; c++) {
      const __bf16* Kr = &Ksm[buf][(c*16 + lr)*64];
      kf0[c] = *(const bf16x8*)(Kr + ((qd       ^ sw) * 8));
      kf1[c] = *(const bf16x8*)(Kr + (((4 + qd) ^ sw) * 8));
    }
    f32x4 s0[4], s1[4];
    #pragma unroll
    for (int c = 0; c < 4; c++) {
      f32x4 z = {};
      z     = __builtin_amdgcn_mfma_f32_16x16x32_bf16(kf0[c], qa00, z, 0, 0, 0);
      s0[c] = __builtin_amdgcn_mfma_f32_16x16x32_bf16(kf1[c], qa01, z, 0, 0, 0);
      f32x4 z2 = {};
      z2    = __builtin_amdgcn_mfma_f32_16x16x32_bf16(kf0[c], qa10, z2, 0, 0, 0);
      s1[c] = __builtin_amdgcn_mfma_f32_16x16x32_bf16(kf1[c], qa11, z2, 0, 0, 0);
    }

    // --- current V frags to registers (consumed NEXT iteration) ---
    bf16x8 vc0[4], vc1[4];
    #pragma unroll
    for (int t = 0; t < 4; t++) {
      const __bf16* Vr = &Vsm[buf][(t*16 + lr)*64];
      vc0[t] = *(const bf16x8*)(Vr + ((qd       ^ sw) * 8));
      vc1[t] = *(const bf16x8*)(Vr + (((4 + qd) ^ sw) * 8));
    }

    // --- PV for previous tile (P drained by this iteration's barrier) ---
    if (kt > 0) {
      bf16x8 pb00 = *(const bf16x8*)(Pp + lr*PSTRIDE + qd*8);
      bf16x8 pb01 = *(const bf16x8*)(Pp + lr*PSTRIDE + 32 + qd*8);
      bf16x8 pb10 = *(const bf16x8*)(Pp + (16+lr)*PSTRIDE + qd*8);
      bf16x8 pb11 = *(const bf16x8*)(Pp + (16+lr)*PSTRIDE + 32 + qd*8);
      #pragma unroll
      for (int t = 0; t < 4; t++) {
        oacc0[t] = __builtin_amdgcn_mfma_f32_16x16x32_bf16(vp0[t], pb00, oacc0[t], 0, 0, 0);
        oacc0[t] = __builtin_amdgcn_mfma_f32_16x16x32_bf16(vp1[t], pb01, oacc0[t], 0, 0, 0);
        oacc1[t] = __builtin_amdgcn_mfma_f32_16x16x32_bf16(vp0[t], pb10, oacc1[t], 0, 0, 0);
        oacc1[t] = __builtin_amdgcn_mfma_f32_16x16x32_bf16(vp1[t], pb11, oacc1[t], 0, 0, 0);
      }
    }

    // --- bias (slow path only), exp2, lsum, write P(cur) — no wait needed ---
    if (hasbias) {
      #pragma unroll
      for (int c = 0; c < 4; c++) {
        float4 b0 = *(const float4*)(bp0 + kt + c*16 + qd*4);
        float4 b1 = *(const float4*)(bp1 + kt + c*16 + qd*4);
        s0[c][0] += b0.x*LOG2E; s0[c][1] += b0.y*LOG2E; s0[c][2] += b0.z*LOG2E; s0[c][3] += b0.w*LOG2E;
        s1[c][0] += b1.x*LOG2E; s1[c][1] += b1.y*LOG2E; s1[c][2] += b1.z*LOG2E; s1[c][3] += b1.w*LOG2E;
      }
    }
    #pragma unroll
    for (int c = 0; c < 4; c++) {
      float p0 = fexp2(s0[c][0]), p1 = fexp2(s0[c][1]), p2 = fexp2(s0[c][2]), p3 = fexp2(s0[c][3]);
      lsum0 += (p0 + p1) + (p2 + p3);
      *(unsigned*)(Pc + lr*PSTRIDE + c*16 + qd*4)     = pk2(p0, p1);
      *(unsigned*)(Pc + lr*PSTRIDE + c*16 + qd*4 + 2) = pk2(p2, p3);
      float r0 = fexp2(s1[c][0]), r1 = fexp2(s1[c][1]), r2 = fexp2(s1[c][2]), r3 = fexp2(s1[c][3]);
      lsum1 += (r0 + r1) + (r2 + r3);
      *(unsigned*)(Pc + (16+lr)*PSTRIDE + c*16 + qd*4)     = pk2(r0, r1);
      *(unsigned*)(Pc + (16+lr)*PSTRIDE + c*16 + qd*4 + 2) = pk2(r2, r3);
    }

    // rotate V frags
    #pragma unroll
    for (int t = 0; t < 4; t++) { vp0[t] = vc0[t]; vp1[t] = vc1[t]; }
  }

  // --- final PV for the last tile (drain our own P writes; wave-local) ---
  asm volatile("s_waitcnt lgkmcnt(0)" ::: "memory");
  {
    const __bf16* Pl = &Pb[((S_/64 - 1)) & 1][wv][0];
    bf16x8 pb00 = *(const bf16x8*)(Pl + lr*PSTRIDE + qd*8);
    bf16x8 pb01 = *(const bf16x8*)(Pl + lr*PSTRIDE + 32 + qd*8);
    bf16x8 pb10 = *(const bf16x8*)(Pl + (16+lr)*PSTRIDE + qd*8);
    bf16x8 pb11 = *(const bf16x8*)(Pl + (16+lr)*PSTRIDE + 32 + qd*8);
    #pragma unroll
    for (int t = 0; t < 4; t++) {
      oacc0[t] = __builtin_amdgcn_mfma_f32_16x16x32_bf16(vp0[t], pb00, oacc0[t], 0, 0, 0);
      oacc0[t] = __builtin_amdgcn_mfma_f32_16x16x32_bf16(vp1[t], pb01, oacc0[t], 0, 0, 0);
      oacc1[t] = __builtin_amdgcn_mfma_f32_16x16x32_bf16(vp0[t], pb10, oacc1[t], 0, 0, 0);
      oacc1[t] = __builtin_amdgcn_mfma_f32_16x16x32_bf16(vp1[t], pb11, oacc1[t], 0, 0, 0);
    }
  }

  lsum0 += __shfl_xor(lsum0, 16); lsum0 += __shfl_xor(lsum0, 32);
  lsum1 += __shfl_xor(lsum1, 16); lsum1 += __shfl_xor(lsum1, 32);
  float inv0 = 1.0f / lsum0;
  float inv1 = 1.0f / lsum1;
  size_t ro0 = ((size_t)(b*S_ + q0 + lr))*HID + h*D_;
  size_t ro1 = ((size_t)(b*S_ + q0 + 16 + lr))*HID + h*D_;
  #pragma unroll
  for (int t = 0; t < 4; t++) {
    union { uint2 u; __bf16 hh[4]; } w0, w1;
    #pragma unroll
    for (int r = 0; r < 4; r++) {
      w0.hh[r] = (__bf16)(oacc0[t][r]*inv0);
      w1.hh[r] = (__bf16)(oacc1[t][r]*inv1);
    }
    *(uint2*)((__bf16*)Ab + ro0 + t*16 + qd*4) = w0.u;
    *(uint2*)((__bf16*)Ab + ro1 + t*16 + qd*4) = w1.u;
  }
}

extern "C" void kernel_launch(void* const* d_in, const int* in_sizes, int n_in,
                              void* d_out, int out_size, void* d_ws, size_t ws_size,
                              hipStream_t stream) {
  (void)in_sizes; (void)n_in; (void)out_size; (void)ws_size;
  const float* x     = (const float*)d_in[0];
  const float* sinu  = (const float*)d_in[1];
  const float* abias = (const float*)d_in[2];
  const float* Wq    = (const float*)d_in[3];
  const float* bq    = (const float*)d_in[4];
  const float* Wk    = (const float*)d_in[5];
  const float* bk    = (const float*)d_in[6];
  const float* Wv    = (const float*)d_in[7];
  const float* bv    = (const float*)d_in[8];
  const float* Wo    = (const float*)d_in[9];

  char* ws = (char*)d_ws;
  __hip_bfloat16* Xb  = (__hip_bfloat16*)(ws + XB_OFF);
  __hip_bfloat16* Wqt = (__hip_bfloat16*)(ws + WQT_OFF);
  __hip_bfloat16* Wkt = (__hip_bfloat16*)(ws + WKT_OFF);
  __hip_bfloat16* Wvt = (__hip_bfloat16*)(ws + WVT_OFF);
  __hip_bfloat16* Wot = (__hip_bfloat16*)(ws + WOT_OFF);
  float*          F   = (float*)(ws + F_OFF);
  __hip_bfloat16* Qh  = (__hip_bfloat16*)(ws + QH_OFF);
  __hip_bfloat16* Kh  = (__hip_bfloat16*)(ws + KH_OFF);
  __hip_bfloat16* Vt  = (__hip_bfloat16*)(ws + VT_OFF);
  __hip_bfloat16* Ab  = (__hip_bfloat16*)(ws + AB_OFF);
  int* flag = (int*)d_out;   // scratch; overwritten by the final GEMM

  hipMemsetAsync(flag, 0, 4, stream);
  prep_kernel<<<10752, 256, 0, stream>>>(x, sinu, abias, Wq, Wk, Wv, Wo,
                                         Xb, F, Wqt, Wkt, Wvt, Wot, flag);

  qkv_kernel<<<dim3(3*HID/128, M_/128), 256, 0, stream>>>(
      Xb, Wqt, bq, bk, bv, F, Qh, Kh, Vt);

  flash_kernel<<<dim3(512), 256, 0, stream>>>(Qh, Kh, Vt, abias, flag, Ab);

  gemm_o64<<<dim3(HID/64, M_/128), 256, 0, stream>>>(Ab, Wot, (float*)d_out);
}